// Round 1
// baseline (1155.841 us; speedup 1.0000x reference)
//
#include <hip/hip_runtime.h>
#include <hip/hip_bf16.h>

#define T 2048
#define NR 1024
#define TOPK 40

static __device__ __forceinline__ float bnscale() { return 0.9999950000374997f; } // 1/sqrt(1+1e-5)

// ---------------------------------------------------------------- kernel 1: bn -> conv q,k (k=3) + v (k=1), t-major outputs + region means
__global__ __launch_bounds__(256) void k_qkv(
    const float* __restrict__ x, const float* __restrict__ n1_g, const float* __restrict__ n1_b,
    const float* __restrict__ wq, const float* __restrict__ bnq_g, const float* __restrict__ bnq_b,
    const float* __restrict__ wk, const float* __restrict__ bnk_g, const float* __restrict__ bnk_b,
    const float* __restrict__ wv,
    float* __restrict__ q_t, float* __restrict__ k_t, float* __restrict__ v_t,
    float* __restrict__ q_r, float* __restrict__ k_r)
{
  const int b = blockIdx.y;
  const int t0 = blockIdx.x * 64;
  const int r0 = blockIdx.x * 32;
  const int tid = threadIdx.x;
  const float INVS = bnscale();

  __shared__ float xn[64][66];   // [c][tt], tt covers t0-1 .. t0+64
  __shared__ float ot[64][66];   // [c_out][t_local]

  for (int i = tid; i < 64 * 66; i += 256) {
    int c = i / 66, tt = i % 66;
    int t = t0 + tt - 1;
    float v = (t >= 0 && t < T) ? x[(size_t)(b * 64 + c) * T + t] : 0.f;
    xn[c][tt] = v * (n1_g[c] * INVS) + n1_b[c];
  }
  __syncthreads();

  const int w = tid >> 6, lane = tid & 63;

  // ---- Q ----
  for (int o = w; o < 64; o += 4) {
    float acc = 0.f;
    const float* wo = wq + o * 192;
    for (int c = 0; c < 64; ++c) {
      acc += xn[c][lane]     * wo[c * 3 + 0];
      acc += xn[c][lane + 1] * wo[c * 3 + 1];
      acc += xn[c][lane + 2] * wo[c * 3 + 2];
    }
    ot[o][lane] = acc * (bnq_g[o] * INVS) + bnq_b[o];
  }
  __syncthreads();
  for (int i = tid; i < 4096; i += 256) {
    int o = i & 63, tt = i >> 6;
    q_t[((size_t)(b * T + t0 + tt)) * 64 + o] = ot[o][tt];
  }
  for (int i = tid; i < 64 * 32; i += 256) {
    int c = i & 63, rr = i >> 6;
    q_r[((size_t)(b * NR + r0 + rr)) * 64 + c] = 0.5f * (ot[c][2 * rr] + ot[c][2 * rr + 1]);
  }
  __syncthreads();

  // ---- K ----
  for (int o = w; o < 64; o += 4) {
    float acc = 0.f;
    const float* wo = wk + o * 192;
    for (int c = 0; c < 64; ++c) {
      acc += xn[c][lane]     * wo[c * 3 + 0];
      acc += xn[c][lane + 1] * wo[c * 3 + 1];
      acc += xn[c][lane + 2] * wo[c * 3 + 2];
    }
    ot[o][lane] = acc * (bnk_g[o] * INVS) + bnk_b[o];
  }
  __syncthreads();
  for (int i = tid; i < 4096; i += 256) {
    int o = i & 63, tt = i >> 6;
    k_t[((size_t)(b * T + t0 + tt)) * 64 + o] = ot[o][tt];
  }
  for (int i = tid; i < 64 * 32; i += 256) {
    int c = i & 63, rr = i >> 6;
    k_r[((size_t)(b * NR + r0 + rr)) * 64 + c] = 0.5f * (ot[c][2 * rr] + ot[c][2 * rr + 1]);
  }
  __syncthreads();

  // ---- V (k=1, no bn) ----
  for (int o = w; o < 64; o += 4) {
    float acc = 0.f;
    const float* wo = wv + o * 64;
    for (int c = 0; c < 64; ++c) acc += xn[c][lane + 1] * wo[c];
    ot[o][lane] = acc;
  }
  __syncthreads();
  for (int i = tid; i < 4096; i += 256) {
    int o = i & 63, tt = i >> 6;
    v_t[((size_t)(b * T + t0 + tt)) * 64 + o] = ot[o][tt];
  }
}

// ---------------------------------------------------------------- kernel 2: region scores + top-40 (indices only)
__global__ __launch_bounds__(256) void k_scores(
    const float* __restrict__ q_r, const float* __restrict__ k_r, int* __restrict__ sel)
{
  const int b = blockIdx.y;
  const int r0 = blockIdx.x * 8;
  const int tid = threadIdx.x;

  __shared__ float sc[8][1024];
  __shared__ float qv[8][64];

  for (int i = tid; i < 512; i += 256) {
    int rr = i >> 6, c = i & 63;
    qv[rr][c] = q_r[((size_t)(b * NR + r0 + rr)) * 64 + c];
  }
  __syncthreads();

  for (int i = tid; i < 8 * 1024; i += 256) {
    int rr = i >> 10, s = i & 1023;
    const float4* kp = (const float4*)(k_r + ((size_t)(b * NR + s)) * 64);
    const float4* qp = (const float4*)qv[rr];
    float acc = 0.f;
#pragma unroll
    for (int c4 = 0; c4 < 16; ++c4) {
      float4 kv = kp[c4];
      float4 qq = qp[c4];
      acc += qq.x * kv.x + qq.y * kv.y + qq.z * kv.z + qq.w * kv.w;
    }
    sc[rr][s] = acc;
  }
  __syncthreads();

  const int w = tid >> 6, lane = tid & 63;
  for (int rr = w; rr < 8; rr += 4) {
    for (int it = 0; it < TOPK; ++it) {
      float bv = -INFINITY;
      int bi = 0x7fffffff;
      for (int s = lane; s < 1024; s += 64) {
        float v = sc[rr][s];
        if (v > bv) { bv = v; bi = s; }   // ascending scan: ties keep lower index
      }
      for (int m = 32; m >= 1; m >>= 1) {
        float ov = __shfl_xor(bv, m);
        int oi = __shfl_xor(bi, m);
        if (ov > bv || (ov == bv && oi < bi)) { bv = ov; bi = oi; }
      }
      if (lane == 0) {
        sel[((size_t)(b * NR + r0 + rr)) * TOPK + it] = bi;
        sc[rr][bi] = -INFINITY;
      }
    }
  }
}

// ---------------------------------------------------------------- kernel 3: gathered attention + lepe depthwise + bias
__global__ __launch_bounds__(256) void k_attn(
    const float* __restrict__ q_t, const float* __restrict__ k_t, const float* __restrict__ v_t,
    const int* __restrict__ sel, const float* __restrict__ lepe_w, const float* __restrict__ lepe_b,
    float* __restrict__ o_t)
{
  const int b = blockIdx.y;
  const int r = blockIdx.x;
  const int tid = threadIdx.x;

  __shared__ float kg[80][65];
  __shared__ float vg[80][65];
  __shared__ float qb[2][64];
  __shared__ int sl[40];
  __shared__ float lg[4][2][84];

  if (tid < 40) sl[tid] = sel[((size_t)(b * NR + r)) * TOPK + tid];
  if (tid >= 128 && tid < 256) {
    int i = tid - 128;
    int s = i >> 6, c = i & 63;
    qb[s][c] = q_t[((size_t)(b * T + r * 2 + s)) * 64 + c];
  }
  __syncthreads();

  for (int i = tid; i < 80 * 64; i += 256) {
    int row = i >> 6, c = i & 63;
    int t = sl[row >> 1] * 2 + (row & 1);
    size_t base = ((size_t)(b * T + t)) * 64 + c;
    kg[row][c] = k_t[base];
    vg[row][c] = v_t[base];
  }
  __syncthreads();

  const int h = tid >> 6, lane = tid & 63;

  for (int flat = lane; flat < 160; flat += 64) {
    int sq = flat / 80;
    int col = flat - sq * 80;
    float acc = 0.f;
#pragma unroll
    for (int d = 0; d < 16; ++d) acc += qb[sq][h * 16 + d] * kg[col][h * 16 + d];
    lg[h][sq][col] = acc * 0.125f;  // 64^-0.5
  }
  __syncthreads();

  for (int sq = 0; sq < 2; ++sq) {
    float a = lg[h][sq][lane];
    float bb = (lane < 16) ? lg[h][sq][64 + lane] : -INFINITY;
    float m = fmaxf(a, bb);
    for (int mm = 32; mm >= 1; mm >>= 1) m = fmaxf(m, __shfl_xor(m, mm));
    float ea = expf(a - m);
    float eb = (lane < 16) ? expf(bb - m) : 0.f;
    float ssum = ea + eb;
    for (int mm = 32; mm >= 1; mm >>= 1) ssum += __shfl_xor(ssum, mm);
    float inv = 1.f / ssum;
    lg[h][sq][lane] = ea * inv;
    if (lane < 16) lg[h][sq][64 + lane] = eb * inv;
  }
  __syncthreads();

  if (lane < 32) {
    int sq = lane >> 4, d = lane & 15;
    int c = h * 16 + d;
    float acc = 0.f;
    for (int col = 0; col < 80; ++col) acc += lg[h][sq][col] * vg[col][c];
    int t = r * 2 + sq;
    float lep = lepe_b[c];
#pragma unroll
    for (int kk = 0; kk < 3; ++kk) {
      int tt = t + kk - 1;
      if (tt >= 0 && tt < T) lep += lepe_w[c * 3 + kk] * v_t[((size_t)(b * T + tt)) * 64 + c];
    }
    o_t[((size_t)(b * T + t)) * 64 + c] = acc + lep;
  }
}

// ---------------------------------------------------------------- kernel 4: out conv + residual + bn2 + fc1 + relu
__global__ __launch_bounds__(256) void k_mix(
    const float* __restrict__ x, const float* __restrict__ o_t,
    const float* __restrict__ out_w, const float* __restrict__ out_b,
    const float* __restrict__ n2_g, const float* __restrict__ n2_b,
    const float* __restrict__ fc1_w, const float* __restrict__ bn1_g, const float* __restrict__ bn1_b,
    float* __restrict__ xres, float* __restrict__ h_t)
{
  const int b = blockIdx.y;
  const int t0 = blockIdx.x * 16;
  const int tid = threadIdx.x;
  const float INVS = bnscale();

  __shared__ float ol[16][65];
  __shared__ float yn[16][65];

  for (int i = tid; i < 1024; i += 256) {
    int tt = i >> 6, c = i & 63;
    ol[tt][c] = o_t[((size_t)(b * T + t0 + tt)) * 64 + c];
  }
  __syncthreads();

  for (int i = tid; i < 1024; i += 256) {
    int c = i & 63, tt = i >> 6;
    float acc = out_b[c];
    const float* wrow = out_w + c * 64;
    for (int cc = 0; cc < 64; ++cc) acc += wrow[cc] * ol[tt][cc];
    float xr = x[(size_t)(b * 64 + c) * T + t0 + tt] + acc;
    xres[((size_t)(b * T + t0 + tt)) * 64 + c] = xr;
    yn[tt][c] = xr * (n2_g[c] * INVS) + n2_b[c];
  }
  __syncthreads();

  for (int i = tid; i < 16 * 128; i += 256) {
    int cc = i & 127, tt = i >> 7;
    float acc = 0.f;
    const float* wrow = fc1_w + cc * 64;
    for (int c = 0; c < 64; ++c) acc += wrow[c] * yn[tt][c];
    float hv = acc * (bn1_g[cc] * INVS) + bn1_b[cc];
    h_t[((size_t)(b * T + t0 + tt)) * 128 + cc] = fmaxf(hv, 0.f);
  }
}

// ---------------------------------------------------------------- kernel 5: FFT -> diag complex filter + relu -> iFFT.real
__device__ __forceinline__ void fft_stages(float* re, float* im, int tid, float sign)
{
  for (int s = 1; s <= 11; ++s) {
    const int half = 1 << (s - 1);
    const float base = sign * 6.283185307179586f / (float)(1 << s);
    for (int k = tid; k < 1024; k += 256) {
      int pos = k & (half - 1);
      int grp = k >> (s - 1);
      int i0 = (grp << s) + pos;
      int i1 = i0 + half;
      float ang = base * (float)pos;
      float sn, cs;
      sincosf(ang, &sn, &cs);
      float xr = re[i1], xi = im[i1];
      float tr = xr * cs - xi * sn;
      float ti = xr * sn + xi * cs;
      float ur = re[i0], ui = im[i0];
      re[i0] = ur + tr; im[i0] = ui + ti;
      re[i1] = ur - tr; im[i1] = ui - ti;
    }
    __syncthreads();
  }
}

__global__ __launch_bounds__(256) void k_fft(
    const float* __restrict__ h_t, const float* __restrict__ fr, const float* __restrict__ fi,
    const float* __restrict__ frb, const float* __restrict__ fib, float* __restrict__ g_t)
{
  const int b = blockIdx.y;
  const int c2 = blockIdx.x;
  const int tid = threadIdx.x;

  __shared__ float re[2048];
  __shared__ float im[2048];

  for (int t = tid; t < 2048; t += 256) {
    re[t] = h_t[((size_t)(b * T + t)) * 128 + c2];
    im[t] = 0.f;
  }
  __syncthreads();

  for (int i = tid; i < 2048; i += 256) {
    int j = __brev((unsigned)i) >> 21;
    if (j > i) {
      float tr = re[i]; re[i] = re[j]; re[j] = tr;
      float ti = im[i]; im[i] = im[j]; im[j] = ti;
    }
  }
  __syncthreads();

  fft_stages(re, im, tid, -1.f);   // forward

  const float SC = 0.022097086912079608f; // 1/sqrt(2048)
  const float fa = fr[c2 * 129];
  const float fb = fi[c2 * 129];
  const float fra = frb[c2];
  const float fia = fib[c2];
  for (int t = tid; t < 2048; t += 256) {
    float rr = re[t] * SC, ii = im[t] * SC;
    re[t] = fmaxf(rr * fa - ii * fb + fra, 0.f);
    im[t] = fmaxf(ii * fa + rr * fb + fia, 0.f);
  }
  __syncthreads();

  for (int i = tid; i < 2048; i += 256) {
    int j = __brev((unsigned)i) >> 21;
    if (j > i) {
      float tr = re[i]; re[i] = re[j]; re[j] = tr;
      float ti = im[i]; im[i] = im[j]; im[j] = ti;
    }
  }
  __syncthreads();

  fft_stages(re, im, tid, +1.f);   // inverse (ortho scale applied at write)

  for (int t = tid; t < 2048; t += 256)
    g_t[((size_t)(b * T + t)) * 128 + c2] = re[t] * SC;
}

// ---------------------------------------------------------------- kernel 6: fc2 + bn + final residual -> d_out (B,64,T)
__global__ __launch_bounds__(256) void k_out(
    const float* __restrict__ g_t, const float* __restrict__ xres,
    const float* __restrict__ fc2_w, const float* __restrict__ bn2_g, const float* __restrict__ bn2_b,
    float* __restrict__ out)
{
  const int b = blockIdx.y;
  const int t0 = blockIdx.x * 16;
  const int tid = threadIdx.x;
  const float INVS = bnscale();

  __shared__ float gl[16][129];

  for (int i = tid; i < 2048; i += 256) {
    int tt = i >> 7, cc = i & 127;
    gl[tt][cc] = g_t[((size_t)(b * T + t0 + tt)) * 128 + cc];
  }
  __syncthreads();

  for (int i = tid; i < 1024; i += 256) {
    int tt = i & 15;
    int c = (i >> 4) & 63;
    float acc = 0.f;
    const float* wrow = fc2_w + c * 128;
#pragma unroll 4
    for (int cc = 0; cc < 128; ++cc) acc += wrow[cc] * gl[tt][cc];
    float val = xres[((size_t)(b * T + t0 + tt)) * 64 + c] + acc * (bn2_g[c] * INVS) + bn2_b[c];
    out[(size_t)(b * 64 + c) * T + t0 + tt] = val;
  }
}

// ----------------------------------------------------------------
extern "C" void kernel_launch(void* const* d_in, const int* in_sizes, int n_in,
                              void* d_out, int out_size, void* d_ws, size_t ws_size,
                              hipStream_t stream) {
  (void)in_sizes; (void)n_in; (void)out_size; (void)ws_size;
  const float* x     = (const float*)d_in[0];
  const float* n1_g  = (const float*)d_in[1];
  const float* n1_b  = (const float*)d_in[2];
  const float* wq    = (const float*)d_in[3];
  const float* bnq_g = (const float*)d_in[4];
  const float* bnq_b = (const float*)d_in[5];
  const float* wk    = (const float*)d_in[6];
  const float* bnk_g = (const float*)d_in[7];
  const float* bnk_b = (const float*)d_in[8];
  const float* wv    = (const float*)d_in[9];
  const float* lepe_w= (const float*)d_in[10];
  const float* lepe_b= (const float*)d_in[11];
  const float* out_w = (const float*)d_in[12];
  const float* out_b = (const float*)d_in[13];
  const float* n2_g  = (const float*)d_in[14];
  const float* n2_b  = (const float*)d_in[15];
  const float* fc1_w = (const float*)d_in[16];
  const float* bn1_g = (const float*)d_in[17];
  const float* bn1_b = (const float*)d_in[18];
  const float* fr    = (const float*)d_in[19];
  const float* fi    = (const float*)d_in[20];
  const float* frb   = (const float*)d_in[21];
  const float* fib   = (const float*)d_in[22];
  const float* fc2_w = (const float*)d_in[23];
  const float* bn2_g = (const float*)d_in[24];
  const float* bn2_b = (const float*)d_in[25];

  float* out = (float*)d_out;
  float* ws  = (float*)d_ws;
  const size_t M1 = (size_t)1 << 20;

  float* q_t  = ws;            // 2M floats
  float* k_t  = ws + 2 * M1;   // 2M
  float* v_t  = ws + 4 * M1;   // 2M
  float* q_r  = ws + 6 * M1;   // 1M
  float* k_r  = ws + 7 * M1;   // 1M
  float* o_t  = ws + 8 * M1;   // 2M
  float* xrs  = ws + 10 * M1;  // 2M
  int*   sel  = (int*)(ws + 12 * M1); // 0.64M ints
  float* h_t  = ws;            // 4M, reuses q_t+k_t (dead after k_attn)
  float* g_t  = ws + 4 * M1;   // 4M, reuses v_t+q_r+k_r (dead after k_attn/k_scores)

  k_qkv<<<dim3(32, 16), 256, 0, stream>>>(x, n1_g, n1_b, wq, bnq_g, bnq_b,
                                          wk, bnk_g, bnk_b, wv, q_t, k_t, v_t, q_r, k_r);
  k_scores<<<dim3(128, 16), 256, 0, stream>>>(q_r, k_r, sel);
  k_attn<<<dim3(1024, 16), 256, 0, stream>>>(q_t, k_t, v_t, sel, lepe_w, lepe_b, o_t);
  k_mix<<<dim3(128, 16), 256, 0, stream>>>(x, o_t, out_w, out_b, n2_g, n2_b,
                                           fc1_w, bn1_g, bn1_b, xrs, h_t);
  k_fft<<<dim3(128, 16), 256, 0, stream>>>(h_t, fr, fi, frb, fib, g_t);
  k_out<<<dim3(128, 16), 256, 0, stream>>>(g_t, xrs, fc2_w, bn2_g, bn2_b, out);
}

// Round 2
// 691.519 us; speedup vs baseline: 1.6715x; 1.6715x over previous
//
#include <hip/hip_runtime.h>
#include <hip/hip_bf16.h>

#define T 2048
#define NR 1024
#define TOPK 40

static __device__ __forceinline__ float bnscale() { return 0.9999950000374997f; } // 1/sqrt(1+1e-5)

// ---------------------------------------------------------------- kernel 1: bn -> conv q,k (k=3) + v (k=1)
// t-major q_t/k_t/v_t + c-major region means q_rc/k_rc
__global__ __launch_bounds__(256) void k_qkv(
    const float* __restrict__ x, const float* __restrict__ n1_g, const float* __restrict__ n1_b,
    const float* __restrict__ wq, const float* __restrict__ bnq_g, const float* __restrict__ bnq_b,
    const float* __restrict__ wk, const float* __restrict__ bnk_g, const float* __restrict__ bnk_b,
    const float* __restrict__ wv,
    float* __restrict__ q_t, float* __restrict__ k_t, float* __restrict__ v_t,
    float* __restrict__ q_rc, float* __restrict__ k_rc)
{
  const int b = blockIdx.y;
  const int t0 = blockIdx.x * 64;
  const int r0 = blockIdx.x * 32;
  const int tid = threadIdx.x;
  const float INVS = bnscale();

  __shared__ float xn[64][67];   // [c][tt], tt covers t0-1 .. t0+64 (pad 67: stride 3 mod 32)
  __shared__ float ot[64][67];   // [c_out][t_local]

  for (int i = tid; i < 64 * 66; i += 256) {
    int c = i / 66, tt = i - c * 66;
    int t = t0 + tt - 1;
    float v = (t >= 0 && t < T) ? x[(size_t)(b * 64 + c) * T + t] : 0.f;
    xn[c][tt] = v * (n1_g[c] * INVS) + n1_b[c];
  }
  __syncthreads();

  const int w = tid >> 6, lane = tid & 63;
  const int ob = __builtin_amdgcn_readfirstlane(w);   // wave-uniform out-channel base -> SGPR weight loads

  float accq[16], acck[16], accv[16];
#pragma unroll
  for (int j = 0; j < 16; ++j) { accq[j] = 0.f; acck[j] = 0.f; accv[j] = 0.f; }

#pragma unroll 1
  for (int c0 = 0; c0 < 64; c0 += 4) {
    float xr[4][3];
#pragma unroll
    for (int cc = 0; cc < 4; ++cc) {
      xr[cc][0] = xn[c0 + cc][lane];
      xr[cc][1] = xn[c0 + cc][lane + 1];
      xr[cc][2] = xn[c0 + cc][lane + 2];
    }
#pragma unroll
    for (int o16 = 0; o16 < 16; ++o16) {
      int o = ob + (o16 << 2);
      const float* wqo = wq + o * 192 + c0 * 3;
      const float* wko = wk + o * 192 + c0 * 3;
      const float* wvo = wv + o * 64 + c0;
      float aq = accq[o16], ak = acck[o16], av = accv[o16];
#pragma unroll
      for (int cc = 0; cc < 4; ++cc) {
        aq += xr[cc][0] * wqo[cc * 3 + 0] + xr[cc][1] * wqo[cc * 3 + 1] + xr[cc][2] * wqo[cc * 3 + 2];
        ak += xr[cc][0] * wko[cc * 3 + 0] + xr[cc][1] * wko[cc * 3 + 1] + xr[cc][2] * wko[cc * 3 + 2];
        av += xr[cc][1] * wvo[cc];
      }
      accq[o16] = aq; acck[o16] = ak; accv[o16] = av;
    }
  }

  // ---- Q: bn, transpose-store, region means ----
#pragma unroll
  for (int o16 = 0; o16 < 16; ++o16) {
    int o = ob + (o16 << 2);
    ot[o][lane] = accq[o16] * (bnq_g[o] * INVS) + bnq_b[o];
  }
  __syncthreads();
  for (int i = tid; i < 4096; i += 256) {
    int c = i & 63, tt = i >> 6;
    q_t[((size_t)(b * T + t0 + tt)) * 64 + c] = ot[c][tt];
  }
  for (int i = tid; i < 2048; i += 256) {
    int rr = i & 31, c = i >> 5;
    q_rc[((size_t)(b * 64 + c)) * NR + r0 + rr] = 0.5f * (ot[c][2 * rr] + ot[c][2 * rr + 1]);
  }
  __syncthreads();

  // ---- K ----
#pragma unroll
  for (int o16 = 0; o16 < 16; ++o16) {
    int o = ob + (o16 << 2);
    ot[o][lane] = acck[o16] * (bnk_g[o] * INVS) + bnk_b[o];
  }
  __syncthreads();
  for (int i = tid; i < 4096; i += 256) {
    int c = i & 63, tt = i >> 6;
    k_t[((size_t)(b * T + t0 + tt)) * 64 + c] = ot[c][tt];
  }
  for (int i = tid; i < 2048; i += 256) {
    int rr = i & 31, c = i >> 5;
    k_rc[((size_t)(b * 64 + c)) * NR + r0 + rr] = 0.5f * (ot[c][2 * rr] + ot[c][2 * rr + 1]);
  }
  __syncthreads();

  // ---- V ----
#pragma unroll
  for (int o16 = 0; o16 < 16; ++o16) {
    int o = ob + (o16 << 2);
    ot[o][lane] = accv[o16];
  }
  __syncthreads();
  for (int i = tid; i < 4096; i += 256) {
    int c = i & 63, tt = i >> 6;
    v_t[((size_t)(b * T + t0 + tt)) * 64 + c] = ot[c][tt];
  }
}

// ---------------------------------------------------------------- kernel 2: region scores (c-major GEMM) + top-40 set
__global__ __launch_bounds__(256) void k_scores(
    const float* __restrict__ q_rc, const float* __restrict__ k_rc, int* __restrict__ sel)
{
  const int b = blockIdx.y;
  const int r0 = blockIdx.x * 4;
  const int tid = threadIdx.x;

  __shared__ float sc[4][1024];
  __shared__ float qs[64][4];

  {
    int c = tid >> 2, rr = tid & 3;
    qs[c][rr] = q_rc[((size_t)(b * 64 + c)) * NR + r0 + rr];
  }
  __syncthreads();

  // each thread owns columns [tid*4, tid*4+4) for all 4 rows
  float a0x=0,a0y=0,a0z=0,a0w=0, a1x=0,a1y=0,a1z=0,a1w=0;
  float a2x=0,a2y=0,a2z=0,a2w=0, a3x=0,a3y=0,a3z=0,a3w=0;
  const float4* kp = (const float4*)(k_rc + ((size_t)b * 64) * NR) + tid;
#pragma unroll 4
  for (int c = 0; c < 64; ++c) {
    float4 kv = kp[c * 256];   // (c row of 1024 floats) / 4
    float q0 = qs[c][0], q1 = qs[c][1], q2 = qs[c][2], q3 = qs[c][3];
    a0x += q0*kv.x; a0y += q0*kv.y; a0z += q0*kv.z; a0w += q0*kv.w;
    a1x += q1*kv.x; a1y += q1*kv.y; a1z += q1*kv.z; a1w += q1*kv.w;
    a2x += q2*kv.x; a2y += q2*kv.y; a2z += q2*kv.z; a2w += q2*kv.w;
    a3x += q3*kv.x; a3y += q3*kv.y; a3z += q3*kv.z; a3w += q3*kv.w;
  }
  *(float4*)&sc[0][tid * 4] = make_float4(a0x, a0y, a0z, a0w);
  *(float4*)&sc[1][tid * 4] = make_float4(a1x, a1y, a1z, a1w);
  *(float4*)&sc[2][tid * 4] = make_float4(a2x, a2y, a2z, a2w);
  *(float4*)&sc[3][tid * 4] = make_float4(a3x, a3y, a3z, a3w);
  __syncthreads();

  // top-40 (set semantics): wave w owns row w; cached per-lane max, only winner rescans
  const int w = tid >> 6, lane = tid & 63;
  float lmax = -INFINITY; int lidx = 0;
#pragma unroll
  for (int j = 0; j < 16; ++j) {
    float v = sc[w][lane + (j << 6)];
    if (v > lmax) { lmax = v; lidx = lane + (j << 6); }
  }
  int* srow = sel + ((size_t)(b * NR + r0 + w)) * TOPK;
  for (int it = 0; it < TOPK; ++it) {
    float bv = lmax; int bi = lidx;
#pragma unroll
    for (int m = 32; m >= 1; m >>= 1) {
      float ov = __shfl_xor(bv, m);
      int oi = __shfl_xor(bi, m);
      if (ov > bv) { bv = ov; bi = oi; }
    }
    if (lane == 0) srow[it] = bi;
    if ((bi & 63) == lane) {
      sc[w][bi] = -INFINITY;
      lmax = -INFINITY; lidx = 0;
#pragma unroll
      for (int j = 0; j < 16; ++j) {
        float v = sc[w][lane + (j << 6)];
        if (v > lmax) { lmax = v; lidx = lane + (j << 6); }
      }
    }
  }
}

// ---------------------------------------------------------------- kernel 3: gathered attention + lepe depthwise + bias
__global__ __launch_bounds__(256) void k_attn(
    const float* __restrict__ q_t, const float* __restrict__ k_t, const float* __restrict__ v_t,
    const int* __restrict__ sel, const float* __restrict__ lepe_w, const float* __restrict__ lepe_b,
    float* __restrict__ o_t)
{
  const int b = blockIdx.y;
  const int r = blockIdx.x;
  const int tid = threadIdx.x;

  __shared__ float kg[80][65];
  __shared__ float vg[80][65];
  __shared__ float qb[2][64];
  __shared__ int sl[40];
  __shared__ float lg[4][2][84];

  if (tid < 40) sl[tid] = sel[((size_t)(b * NR + r)) * TOPK + tid];
  if (tid >= 128 && tid < 256) {
    int i = tid - 128;
    int s = i >> 6, c = i & 63;
    qb[s][c] = q_t[((size_t)(b * T + r * 2 + s)) * 64 + c];
  }
  __syncthreads();

  for (int i = tid; i < 80 * 64; i += 256) {
    int row = i >> 6, c = i & 63;
    int t = sl[row >> 1] * 2 + (row & 1);
    size_t base = ((size_t)(b * T + t)) * 64 + c;
    kg[row][c] = k_t[base];
    vg[row][c] = v_t[base];
  }
  __syncthreads();

  const int h = tid >> 6, lane = tid & 63;

  for (int flat = lane; flat < 160; flat += 64) {
    int sq = flat / 80;
    int col = flat - sq * 80;
    float acc = 0.f;
#pragma unroll
    for (int d = 0; d < 16; ++d) acc += qb[sq][h * 16 + d] * kg[col][h * 16 + d];
    lg[h][sq][col] = acc * 0.125f;  // 64^-0.5
  }
  __syncthreads();

  for (int sq = 0; sq < 2; ++sq) {
    float a = lg[h][sq][lane];
    float bb = (lane < 16) ? lg[h][sq][64 + lane] : -INFINITY;
    float m = fmaxf(a, bb);
    for (int mm = 32; mm >= 1; mm >>= 1) m = fmaxf(m, __shfl_xor(m, mm));
    float ea = expf(a - m);
    float eb = (lane < 16) ? expf(bb - m) : 0.f;
    float ssum = ea + eb;
    for (int mm = 32; mm >= 1; mm >>= 1) ssum += __shfl_xor(ssum, mm);
    float inv = 1.f / ssum;
    lg[h][sq][lane] = ea * inv;
    if (lane < 16) lg[h][sq][64 + lane] = eb * inv;
  }
  __syncthreads();

  if (lane < 32) {
    int sq = lane >> 4, d = lane & 15;
    int c = h * 16 + d;
    float acc = 0.f;
    for (int col = 0; col < 80; ++col) acc += lg[h][sq][col] * vg[col][c];
    int t = r * 2 + sq;
    float lep = lepe_b[c];
#pragma unroll
    for (int kk = 0; kk < 3; ++kk) {
      int tt = t + kk - 1;
      if (tt >= 0 && tt < T) lep += lepe_w[c * 3 + kk] * v_t[((size_t)(b * T + tt)) * 64 + c];
    }
    o_t[((size_t)(b * T + t)) * 64 + c] = acc + lep;
  }
}

// ---------------------------------------------------------------- kernel 4: out conv + residual + bn2 + fc1 + relu -> h_c (c-major)
__global__ __launch_bounds__(256) void k_mix(
    const float* __restrict__ x, const float* __restrict__ o_t,
    const float* __restrict__ out_w, const float* __restrict__ out_b,
    const float* __restrict__ n2_g, const float* __restrict__ n2_b,
    const float* __restrict__ fc1_w, const float* __restrict__ bn1_g, const float* __restrict__ bn1_b,
    float* __restrict__ xres, float* __restrict__ h_c)
{
  const int b = blockIdx.y;
  const int t0 = blockIdx.x * 16;
  const int tid = threadIdx.x;
  const float INVS = bnscale();

  __shared__ float ol[16][65];
  __shared__ float yn[16][65];
  __shared__ float xl[16][65];
  __shared__ float wo[64][65];    // out_w transposed: wo[cc][c]
  __shared__ float w1[128][65];   // fc1_w natural [cc][c]
  __shared__ float res2[128][17];

  for (int i = tid; i < 1024; i += 256) {
    int tt = i >> 6, c = i & 63;
    ol[tt][c] = o_t[((size_t)(b * T + t0 + tt)) * 64 + c];
  }
  for (int i = tid; i < 1024; i += 256) {
    int c = i >> 4, tt = i & 15;
    xl[tt][c] = x[(size_t)(b * 64 + c) * T + t0 + tt];
  }
  for (int i = tid; i < 4096; i += 256) {
    int c = i >> 6, cc = i & 63;
    wo[cc][c] = out_w[i];
  }
  for (int i = tid; i < 8192; i += 256) {
    int cc = i >> 6, c = i & 63;
    w1[cc][c] = fc1_w[i];
  }
  __syncthreads();

  // out conv: thread = (c, 4 tt's)
  {
    const int c = tid & 63, grp = tid >> 6;
    float a0 = out_b[c], a1 = a0, a2 = a0, a3 = a0;
    for (int cc = 0; cc < 64; ++cc) {
      float wv = wo[cc][c];
      a0 += wv * ol[grp * 4 + 0][cc];
      a1 += wv * ol[grp * 4 + 1][cc];
      a2 += wv * ol[grp * 4 + 2][cc];
      a3 += wv * ol[grp * 4 + 3][cc];
    }
    float g2 = n2_g[c] * INVS, b2 = n2_b[c];
    float av[4] = {a0, a1, a2, a3};
#pragma unroll
    for (int j = 0; j < 4; ++j) {
      int tt = grp * 4 + j;
      float xr = xl[tt][c] + av[j];
      xres[((size_t)(b * T + t0 + tt)) * 64 + c] = xr;
      yn[tt][c] = xr * g2 + b2;
    }
  }
  __syncthreads();

  // fc1 + bn1 + relu: thread = (cc, 8 tt's)
  {
    const int cc = tid & 127, half = tid >> 7;
    float acc[8];
#pragma unroll
    for (int j = 0; j < 8; ++j) acc[j] = 0.f;
    for (int c = 0; c < 64; ++c) {
      float wv = w1[cc][c];
#pragma unroll
      for (int j = 0; j < 8; ++j) acc[j] += wv * yn[half * 8 + j][c];
    }
    float g1 = bn1_g[cc] * INVS, b1 = bn1_b[cc];
#pragma unroll
    for (int j = 0; j < 8; ++j)
      res2[cc][half * 8 + j] = fmaxf(acc[j] * g1 + b1, 0.f);
  }
  __syncthreads();

  for (int i = tid; i < 2048; i += 256) {
    int tt = i & 15, cc = i >> 4;
    h_c[((size_t)(b * 128 + cc)) * T + t0 + tt] = res2[cc][tt];
  }
}

// ---------------------------------------------------------------- kernel 5: FFT(DIF) -> diag filter + relu -> iFFT(DIT), c-major I/O
__global__ __launch_bounds__(256) void k_fft(
    const float* __restrict__ h_c, const float* __restrict__ fr, const float* __restrict__ fi,
    const float* __restrict__ frb, const float* __restrict__ fib, float* __restrict__ g_c)
{
  const int b = blockIdx.y;
  const int c2 = blockIdx.x;
  const int tid = threadIdx.x;

  __shared__ float re[2048];
  __shared__ float im[2048];
  __shared__ float twr[1024];
  __shared__ float twi[1024];

  for (int i = tid; i < 1024; i += 256) {
    float ang = -6.283185307179586f * (float)i * (1.0f / 2048.0f);
    float sn, cs;
    sincosf(ang, &sn, &cs);
    twr[i] = cs; twi[i] = sn;
  }
  const float* hrow = h_c + ((size_t)(b * 128 + c2)) * T;
  for (int t = tid; t < 2048; t += 256) {
    re[t] = hrow[t];
    im[t] = 0.f;
  }
  __syncthreads();

  // forward DIF: natural in -> bit-reversed out
  for (int s = 11; s >= 1; --s) {
    const int half = 1 << (s - 1);
    for (int k = tid; k < 1024; k += 256) {
      int pos = k & (half - 1);
      int grp = k >> (s - 1);
      int i0 = (grp << s) + pos;
      int i1 = i0 + half;
      int j = pos << (11 - s);
      float wr = twr[j], wi = twi[j];
      float ur = re[i0], ui = im[i0];
      float vr = re[i1], vi = im[i1];
      re[i0] = ur + vr; im[i0] = ui + vi;
      float dr = ur - vr, di = ui - vi;
      re[i1] = dr * wr - di * wi;
      im[i1] = dr * wi + di * wr;
    }
    __syncthreads();
  }

  // elementwise spectral filter (order-independent)
  const float SC = 0.022097086912079608f; // 1/sqrt(2048)
  const float fa = fr[c2 * 129];
  const float fb = fi[c2 * 129];
  const float fra = frb[c2];
  const float fia = fib[c2];
  for (int t = tid; t < 2048; t += 256) {
    float rr = re[t] * SC, ii = im[t] * SC;
    re[t] = fmaxf(rr * fa - ii * fb + fra, 0.f);
    im[t] = fmaxf(ii * fa + rr * fb + fia, 0.f);
  }
  __syncthreads();

  // inverse DIT: bit-reversed in -> natural out
  for (int s = 1; s <= 11; ++s) {
    const int half = 1 << (s - 1);
    for (int k = tid; k < 1024; k += 256) {
      int pos = k & (half - 1);
      int grp = k >> (s - 1);
      int i0 = (grp << s) + pos;
      int i1 = i0 + half;
      int j = pos << (11 - s);
      float wr = twr[j], wi = -twi[j];
      float xr = re[i1], xi = im[i1];
      float tr = xr * wr - xi * wi;
      float ti = xr * wi + xi * wr;
      float ur = re[i0], ui = im[i0];
      re[i0] = ur + tr; im[i0] = ui + ti;
      re[i1] = ur - tr; im[i1] = ui - ti;
    }
    __syncthreads();
  }

  float* grow = g_c + ((size_t)(b * 128 + c2)) * T;
  for (int t = tid; t < 2048; t += 256)
    grow[t] = re[t] * SC;
}

// ---------------------------------------------------------------- kernel 6: fc2 + bn + final residual -> d_out (B,64,T)
__global__ __launch_bounds__(256) void k_out(
    const float* __restrict__ g_c, const float* __restrict__ xres,
    const float* __restrict__ fc2_w, const float* __restrict__ bn2_g, const float* __restrict__ bn2_b,
    float* __restrict__ out)
{
  const int b = blockIdx.y;
  const int t0 = blockIdx.x * 16;
  const int tid = threadIdx.x;
  const float INVS = bnscale();

  __shared__ float gl[16][129];
  __shared__ float w2[128][65];   // fc2_w transposed: w2[cc][c]
  __shared__ float res[64][17];

  for (int i = tid; i < 2048; i += 256) {
    int tt = i & 15, cc = i >> 4;
    gl[tt][cc] = g_c[((size_t)(b * 128 + cc)) * T + t0 + tt];
  }
  for (int i = tid; i < 8192; i += 256) {
    int c = i >> 7, cc = i & 127;
    w2[cc][c] = fc2_w[i];
  }
  __syncthreads();

  {
    const int c = tid & 63, grp = tid >> 6;
    float a0 = 0.f, a1 = 0.f, a2 = 0.f, a3 = 0.f;
    for (int cc = 0; cc < 128; ++cc) {
      float wv = w2[cc][c];
      a0 += wv * gl[grp * 4 + 0][cc];
      a1 += wv * gl[grp * 4 + 1][cc];
      a2 += wv * gl[grp * 4 + 2][cc];
      a3 += wv * gl[grp * 4 + 3][cc];
    }
    float g2 = bn2_g[c] * INVS, b2 = bn2_b[c];
    float av[4] = {a0, a1, a2, a3};
#pragma unroll
    for (int j = 0; j < 4; ++j) {
      int tt = grp * 4 + j;
      // coalesced xres read in this mapping (lanes = consecutive c)
      res[c][tt] = xres[((size_t)(b * T + t0 + tt)) * 64 + c] + av[j] * g2 + b2;
    }
  }
  __syncthreads();

  for (int i = tid; i < 1024; i += 256) {
    int tt = i & 15, c = i >> 4;
    out[(size_t)(b * 64 + c) * T + t0 + tt] = res[c][tt];
  }
}

// ----------------------------------------------------------------
extern "C" void kernel_launch(void* const* d_in, const int* in_sizes, int n_in,
                              void* d_out, int out_size, void* d_ws, size_t ws_size,
                              hipStream_t stream) {
  (void)in_sizes; (void)n_in; (void)out_size; (void)ws_size;
  const float* x     = (const float*)d_in[0];
  const float* n1_g  = (const float*)d_in[1];
  const float* n1_b  = (const float*)d_in[2];
  const float* wq    = (const float*)d_in[3];
  const float* bnq_g = (const float*)d_in[4];
  const float* bnq_b = (const float*)d_in[5];
  const float* wk    = (const float*)d_in[6];
  const float* bnk_g = (const float*)d_in[7];
  const float* bnk_b = (const float*)d_in[8];
  const float* wv    = (const float*)d_in[9];
  const float* lepe_w= (const float*)d_in[10];
  const float* lepe_b= (const float*)d_in[11];
  const float* out_w = (const float*)d_in[12];
  const float* out_b = (const float*)d_in[13];
  const float* n2_g  = (const float*)d_in[14];
  const float* n2_b  = (const float*)d_in[15];
  const float* fc1_w = (const float*)d_in[16];
  const float* bn1_g = (const float*)d_in[17];
  const float* bn1_b = (const float*)d_in[18];
  const float* fr    = (const float*)d_in[19];
  const float* fi    = (const float*)d_in[20];
  const float* frb   = (const float*)d_in[21];
  const float* fib   = (const float*)d_in[22];
  const float* fc2_w = (const float*)d_in[23];
  const float* bn2_g = (const float*)d_in[24];
  const float* bn2_b = (const float*)d_in[25];

  float* out = (float*)d_out;
  float* ws  = (float*)d_ws;
  const size_t M1 = (size_t)1 << 20;

  float* q_t  = ws;            // 2M floats
  float* k_t  = ws + 2 * M1;   // 2M
  float* v_t  = ws + 4 * M1;   // 2M
  float* q_rc = ws + 6 * M1;   // 1M  (c-major [b][c][r])
  float* k_rc = ws + 7 * M1;   // 1M
  float* o_t  = ws + 8 * M1;   // 2M
  float* xrs  = ws + 10 * M1;  // 2M
  int*   sel  = (int*)(ws + 12 * M1); // 0.64M ints
  float* h_c  = ws;            // 4M c-major [b][cc][t], reuses q_t+k_t (dead after k_attn)
  float* g_c  = ws + 4 * M1;   // 4M c-major, reuses v_t+q_rc+k_rc

  k_qkv<<<dim3(32, 16), 256, 0, stream>>>(x, n1_g, n1_b, wq, bnq_g, bnq_b,
                                          wk, bnk_g, bnk_b, wv, q_t, k_t, v_t, q_rc, k_rc);
  k_scores<<<dim3(256, 16), 256, 0, stream>>>(q_rc, k_rc, sel);
  k_attn<<<dim3(1024, 16), 256, 0, stream>>>(q_t, k_t, v_t, sel, lepe_w, lepe_b, o_t);
  k_mix<<<dim3(128, 16), 256, 0, stream>>>(x, o_t, out_w, out_b, n2_g, n2_b,
                                           fc1_w, bn1_g, bn1_b, xrs, h_c);
  k_fft<<<dim3(128, 16), 256, 0, stream>>>(h_c, fr, fi, frb, fib, g_c);
  k_out<<<dim3(128, 16), 256, 0, stream>>>(g_c, xrs, fc2_w, bn2_g, bn2_b, out);
}

// Round 3
// 604.281 us; speedup vs baseline: 1.9128x; 1.1444x over previous
//
#include <hip/hip_runtime.h>
#include <hip/hip_bf16.h>

#define T 2048
#define NR 1024
#define TOPK 40

static __device__ __forceinline__ float bnscale() { return 0.9999950000374997f; } // 1/sqrt(1+1e-5)

// ---------------------------------------------------------------- kernel 1: bn -> conv q,k (k=3) + v (k=1)
// t-major q_t/k_t/v_t + c-major region means q_rc/k_rc
__global__ __launch_bounds__(256) void k_qkv(
    const float* __restrict__ x, const float* __restrict__ n1_g, const float* __restrict__ n1_b,
    const float* __restrict__ wq, const float* __restrict__ bnq_g, const float* __restrict__ bnq_b,
    const float* __restrict__ wk, const float* __restrict__ bnk_g, const float* __restrict__ bnk_b,
    const float* __restrict__ wv,
    float* __restrict__ q_t, float* __restrict__ k_t, float* __restrict__ v_t,
    float* __restrict__ q_rc, float* __restrict__ k_rc)
{
  const int b = blockIdx.y;
  const int t0 = blockIdx.x * 64;
  const int r0 = blockIdx.x * 32;
  const int tid = threadIdx.x;
  const float INVS = bnscale();

  __shared__ float xn[64][67];   // [c][tt], tt covers t0-1 .. t0+64 (pad 67: stride 3 mod 32)
  __shared__ float ot[64][67];   // [c_out][t_local]

  for (int i = tid; i < 64 * 66; i += 256) {
    int c = i / 66, tt = i - c * 66;
    int t = t0 + tt - 1;
    float v = (t >= 0 && t < T) ? x[(size_t)(b * 64 + c) * T + t] : 0.f;
    xn[c][tt] = v * (n1_g[c] * INVS) + n1_b[c];
  }
  __syncthreads();

  const int w = tid >> 6, lane = tid & 63;
  const int ob = __builtin_amdgcn_readfirstlane(w);   // wave-uniform out-channel base -> SGPR weight loads

  float accq[16], acck[16], accv[16];
#pragma unroll
  for (int j = 0; j < 16; ++j) { accq[j] = 0.f; acck[j] = 0.f; accv[j] = 0.f; }

#pragma unroll 1
  for (int c0 = 0; c0 < 64; c0 += 4) {
    float xr[4][3];
#pragma unroll
    for (int cc = 0; cc < 4; ++cc) {
      xr[cc][0] = xn[c0 + cc][lane];
      xr[cc][1] = xn[c0 + cc][lane + 1];
      xr[cc][2] = xn[c0 + cc][lane + 2];
    }
#pragma unroll
    for (int o16 = 0; o16 < 16; ++o16) {
      int o = ob + (o16 << 2);
      const float* wqo = wq + o * 192 + c0 * 3;
      const float* wko = wk + o * 192 + c0 * 3;
      const float* wvo = wv + o * 64 + c0;
      float aq = accq[o16], ak = acck[o16], av = accv[o16];
#pragma unroll
      for (int cc = 0; cc < 4; ++cc) {
        aq += xr[cc][0] * wqo[cc * 3 + 0] + xr[cc][1] * wqo[cc * 3 + 1] + xr[cc][2] * wqo[cc * 3 + 2];
        ak += xr[cc][0] * wko[cc * 3 + 0] + xr[cc][1] * wko[cc * 3 + 1] + xr[cc][2] * wko[cc * 3 + 2];
        av += xr[cc][1] * wvo[cc];
      }
      accq[o16] = aq; acck[o16] = ak; accv[o16] = av;
    }
  }

  // ---- Q: bn, transpose-store, region means ----
#pragma unroll
  for (int o16 = 0; o16 < 16; ++o16) {
    int o = ob + (o16 << 2);
    ot[o][lane] = accq[o16] * (bnq_g[o] * INVS) + bnq_b[o];
  }
  __syncthreads();
  for (int i = tid; i < 4096; i += 256) {
    int c = i & 63, tt = i >> 6;
    q_t[((size_t)(b * T + t0 + tt)) * 64 + c] = ot[c][tt];
  }
  for (int i = tid; i < 2048; i += 256) {
    int rr = i & 31, c = i >> 5;
    q_rc[((size_t)(b * 64 + c)) * NR + r0 + rr] = 0.5f * (ot[c][2 * rr] + ot[c][2 * rr + 1]);
  }
  __syncthreads();

  // ---- K ----
#pragma unroll
  for (int o16 = 0; o16 < 16; ++o16) {
    int o = ob + (o16 << 2);
    ot[o][lane] = acck[o16] * (bnk_g[o] * INVS) + bnk_b[o];
  }
  __syncthreads();
  for (int i = tid; i < 4096; i += 256) {
    int c = i & 63, tt = i >> 6;
    k_t[((size_t)(b * T + t0 + tt)) * 64 + c] = ot[c][tt];
  }
  for (int i = tid; i < 2048; i += 256) {
    int rr = i & 31, c = i >> 5;
    k_rc[((size_t)(b * 64 + c)) * NR + r0 + rr] = 0.5f * (ot[c][2 * rr] + ot[c][2 * rr + 1]);
  }
  __syncthreads();

  // ---- V ----
#pragma unroll
  for (int o16 = 0; o16 < 16; ++o16) {
    int o = ob + (o16 << 2);
    ot[o][lane] = accv[o16];
  }
  __syncthreads();
  for (int i = tid; i < 4096; i += 256) {
    int c = i & 63, tt = i >> 6;
    v_t[((size_t)(b * T + t0 + tt)) * 64 + c] = ot[c][tt];
  }
}

// ---------------------------------------------------------------- kernel 2: region scores (c-major GEMM) + top-40 set
__global__ __launch_bounds__(256) void k_scores(
    const float* __restrict__ q_rc, const float* __restrict__ k_rc, int* __restrict__ sel)
{
  const int b = blockIdx.y;
  const int r0 = blockIdx.x * 4;
  const int tid = threadIdx.x;

  __shared__ float sc[4][1024];
  __shared__ float qs[64][4];

  {
    int c = tid >> 2, rr = tid & 3;
    qs[c][rr] = q_rc[((size_t)(b * 64 + c)) * NR + r0 + rr];
  }
  __syncthreads();

  // each thread owns columns [tid*4, tid*4+4) for all 4 rows
  float a0x=0,a0y=0,a0z=0,a0w=0, a1x=0,a1y=0,a1z=0,a1w=0;
  float a2x=0,a2y=0,a2z=0,a2w=0, a3x=0,a3y=0,a3z=0,a3w=0;
  const float4* kp = (const float4*)(k_rc + ((size_t)b * 64) * NR) + tid;
#pragma unroll 4
  for (int c = 0; c < 64; ++c) {
    float4 kv = kp[c * 256];   // (c row of 1024 floats) / 4
    float q0 = qs[c][0], q1 = qs[c][1], q2 = qs[c][2], q3 = qs[c][3];
    a0x += q0*kv.x; a0y += q0*kv.y; a0z += q0*kv.z; a0w += q0*kv.w;
    a1x += q1*kv.x; a1y += q1*kv.y; a1z += q1*kv.z; a1w += q1*kv.w;
    a2x += q2*kv.x; a2y += q2*kv.y; a2z += q2*kv.z; a2w += q2*kv.w;
    a3x += q3*kv.x; a3y += q3*kv.y; a3z += q3*kv.z; a3w += q3*kv.w;
  }
  *(float4*)&sc[0][tid * 4] = make_float4(a0x, a0y, a0z, a0w);
  *(float4*)&sc[1][tid * 4] = make_float4(a1x, a1y, a1z, a1w);
  *(float4*)&sc[2][tid * 4] = make_float4(a2x, a2y, a2z, a2w);
  *(float4*)&sc[3][tid * 4] = make_float4(a3x, a3y, a3z, a3w);
  __syncthreads();

  // top-40 (set semantics): wave w owns row w; cached per-lane max, only winner rescans
  const int w = tid >> 6, lane = tid & 63;
  float lmax = -INFINITY; int lidx = 0;
#pragma unroll
  for (int j = 0; j < 16; ++j) {
    float v = sc[w][lane + (j << 6)];
    if (v > lmax) { lmax = v; lidx = lane + (j << 6); }
  }
  int* srow = sel + ((size_t)(b * NR + r0 + w)) * TOPK;
  for (int it = 0; it < TOPK; ++it) {
    float bv = lmax; int bi = lidx;
#pragma unroll
    for (int m = 32; m >= 1; m >>= 1) {
      float ov = __shfl_xor(bv, m);
      int oi = __shfl_xor(bi, m);
      if (ov > bv) { bv = ov; bi = oi; }
    }
    if (lane == 0) srow[it] = bi;
    if ((bi & 63) == lane) {
      sc[w][bi] = -INFINITY;
      lmax = -INFINITY; lidx = 0;
#pragma unroll
      for (int j = 0; j < 16; ++j) {
        float v = sc[w][lane + (j << 6)];
        if (v > lmax) { lmax = v; lidx = lane + (j << 6); }
      }
    }
  }
}

// ---------------------------------------------------------------- kernel 3: gathered attention + lepe depthwise + bias
// K staged in LDS; V consumed directly from global (coalesced row reads); ~26KB LDS -> 6 blocks/CU
__global__ __launch_bounds__(256) void k_attn(
    const float* __restrict__ q_t, const float* __restrict__ k_t, const float* __restrict__ v_t,
    const int* __restrict__ sel, const float* __restrict__ lepe_w, const float* __restrict__ lepe_b,
    float* __restrict__ o_t)
{
  const int b = blockIdx.y;
  const int r = blockIdx.x;
  const int tid = threadIdx.x;

  __shared__ float kg[80][65];      // gathered K, 20.8 KB
  __shared__ float qb[2][64];
  __shared__ int   sl[40];
  __shared__ float lg[4][2][84];    // probs per head
  __shared__ float vl[4][64];       // v rows 2r-1..2r+2 for lepe
  __shared__ float part[2][2][64];  // PV partials [half][sq][c]

  if (tid < 40) sl[tid] = sel[((size_t)(b * NR + r)) * TOPK + tid];
  if (tid >= 128 && tid < 256) {
    int i = tid - 128;
    int s = i >> 6, c = i & 63;
    qb[s][c] = q_t[((size_t)(b * T + r * 2 + s)) * 64 + c];
  }
  {
    int idx = tid >> 6, c = tid & 63;
    int t = 2 * r - 1 + idx;
    vl[idx][c] = (t >= 0 && t < T) ? v_t[((size_t)(b * T + t)) * 64 + c] : 0.f;
  }
  __syncthreads();

  for (int i = tid; i < 80 * 64; i += 256) {
    int row = i >> 6, c = i & 63;
    int t = sl[row >> 1] * 2 + (row & 1);
    kg[row][c] = k_t[((size_t)(b * T + t)) * 64 + c];
  }
  __syncthreads();

  const int h = tid >> 6, lane = tid & 63;

  // QK^T: wave h computes its head's 2x80 logits
  for (int flat = lane; flat < 160; flat += 64) {
    int sq = flat / 80;
    int col = flat - sq * 80;
    float acc = 0.f;
#pragma unroll
    for (int d = 0; d < 16; ++d) acc += qb[sq][h * 16 + d] * kg[col][h * 16 + d];
    lg[h][sq][col] = acc * 0.125f;  // 64^-0.5
  }

  // softmax (wave-local: lg[h] written and read by wave h only)
  for (int sq = 0; sq < 2; ++sq) {
    float a = lg[h][sq][lane];
    float bb = (lane < 16) ? lg[h][sq][64 + lane] : -INFINITY;
    float m = fmaxf(a, bb);
    for (int mm = 32; mm >= 1; mm >>= 1) m = fmaxf(m, __shfl_xor(m, mm));
    float ea = expf(a - m);
    float eb = (lane < 16) ? expf(bb - m) : 0.f;
    float ssum = ea + eb;
    for (int mm = 32; mm >= 1; mm >>= 1) ssum += __shfl_xor(ssum, mm);
    float inv = 1.f / ssum;
    lg[h][sq][lane] = ea * inv;
    if (lane < 16) lg[h][sq][64 + lane] = eb * inv;
  }
  __syncthreads();

  // PV: thread = (half, sq, c); V rows read coalesced from global
  {
    const int c = tid & 63, j = tid >> 6;
    const int sq = j & 1, half = j >> 1;
    const float* vbase = v_t + ((size_t)b * T) * 64 + c;
    const int hh = c >> 4;
    float acc = 0.f;
#pragma unroll 4
    for (int cc = 0; cc < 40; ++cc) {
      int col = half * 40 + cc;
      int t = sl[col >> 1] * 2 + (col & 1);
      acc += lg[hh][sq][col] * vbase[(size_t)t * 64];
    }
    part[half][sq][c] = acc;
  }
  __syncthreads();

  if (tid < 128) {
    int sq = tid >> 6, c = tid & 63;
    float o = part[0][sq][c] + part[1][sq][c];
    float lep = lepe_b[c];
#pragma unroll
    for (int kk = 0; kk < 3; ++kk) lep += lepe_w[c * 3 + kk] * vl[sq + kk][c];
    o_t[((size_t)(b * T + 2 * r + sq)) * 64 + c] = o + lep;
  }
}

// ---------------------------------------------------------------- kernel 4: out conv + residual + bn2 + fc1 + relu -> h_c (c-major)
__global__ __launch_bounds__(256) void k_mix(
    const float* __restrict__ x, const float* __restrict__ o_t,
    const float* __restrict__ out_w, const float* __restrict__ out_b,
    const float* __restrict__ n2_g, const float* __restrict__ n2_b,
    const float* __restrict__ fc1_w, const float* __restrict__ bn1_g, const float* __restrict__ bn1_b,
    float* __restrict__ xres, float* __restrict__ h_c)
{
  const int b = blockIdx.y;
  const int t0 = blockIdx.x * 16;
  const int tid = threadIdx.x;
  const float INVS = bnscale();

  __shared__ float ol[16][65];
  __shared__ float yn[16][65];
  __shared__ float xl[16][65];
  __shared__ float wo[64][65];    // out_w transposed: wo[cc][c]
  __shared__ float w1[128][65];   // fc1_w natural [cc][c]
  __shared__ float res2[128][17];

  for (int i = tid; i < 1024; i += 256) {
    int tt = i >> 6, c = i & 63;
    ol[tt][c] = o_t[((size_t)(b * T + t0 + tt)) * 64 + c];
  }
  for (int i = tid; i < 1024; i += 256) {
    int c = i >> 4, tt = i & 15;
    xl[tt][c] = x[(size_t)(b * 64 + c) * T + t0 + tt];
  }
  for (int i = tid; i < 4096; i += 256) {
    int c = i >> 6, cc = i & 63;
    wo[cc][c] = out_w[i];
  }
  for (int i = tid; i < 8192; i += 256) {
    int cc = i >> 6, c = i & 63;
    w1[cc][c] = fc1_w[i];
  }
  __syncthreads();

  // out conv: thread = (c, 4 tt's)
  {
    const int c = tid & 63, grp = tid >> 6;
    float a0 = out_b[c], a1 = a0, a2 = a0, a3 = a0;
    for (int cc = 0; cc < 64; ++cc) {
      float wv = wo[cc][c];
      a0 += wv * ol[grp * 4 + 0][cc];
      a1 += wv * ol[grp * 4 + 1][cc];
      a2 += wv * ol[grp * 4 + 2][cc];
      a3 += wv * ol[grp * 4 + 3][cc];
    }
    float g2 = n2_g[c] * INVS, b2 = n2_b[c];
    float av[4] = {a0, a1, a2, a3};
#pragma unroll
    for (int j = 0; j < 4; ++j) {
      int tt = grp * 4 + j;
      float xr = xl[tt][c] + av[j];
      xres[((size_t)(b * T + t0 + tt)) * 64 + c] = xr;
      yn[tt][c] = xr * g2 + b2;
    }
  }
  __syncthreads();

  // fc1 + bn1 + relu: thread = (cc, 8 tt's)
  {
    const int cc = tid & 127, half = tid >> 7;
    float acc[8];
#pragma unroll
    for (int j = 0; j < 8; ++j) acc[j] = 0.f;
    for (int c = 0; c < 64; ++c) {
      float wv = w1[cc][c];
#pragma unroll
      for (int j = 0; j < 8; ++j) acc[j] += wv * yn[half * 8 + j][c];
    }
    float g1 = bn1_g[cc] * INVS, b1 = bn1_b[cc];
#pragma unroll
    for (int j = 0; j < 8; ++j)
      res2[cc][half * 8 + j] = fmaxf(acc[j] * g1 + b1, 0.f);
  }
  __syncthreads();

  for (int i = tid; i < 2048; i += 256) {
    int tt = i & 15, cc = i >> 4;
    h_c[((size_t)(b * 128 + cc)) * T + t0 + tt] = res2[cc][tt];
  }
}

// ---------------------------------------------------------------- kernel 5: FFT(DIF) -> diag filter + relu -> iFFT(DIT), c-major I/O
__global__ __launch_bounds__(256) void k_fft(
    const float* __restrict__ h_c, const float* __restrict__ fr, const float* __restrict__ fi,
    const float* __restrict__ frb, const float* __restrict__ fib, float* __restrict__ g_c)
{
  const int b = blockIdx.y;
  const int c2 = blockIdx.x;
  const int tid = threadIdx.x;

  __shared__ float re[2048];
  __shared__ float im[2048];
  __shared__ float twr[1024];
  __shared__ float twi[1024];

  for (int i = tid; i < 1024; i += 256) {
    float ang = -6.283185307179586f * (float)i * (1.0f / 2048.0f);
    float sn, cs;
    sincosf(ang, &sn, &cs);
    twr[i] = cs; twi[i] = sn;
  }
  const float* hrow = h_c + ((size_t)(b * 128 + c2)) * T;
  for (int t = tid; t < 2048; t += 256) {
    re[t] = hrow[t];
    im[t] = 0.f;
  }
  __syncthreads();

  // forward DIF: natural in -> bit-reversed out
  for (int s = 11; s >= 1; --s) {
    const int half = 1 << (s - 1);
    for (int k = tid; k < 1024; k += 256) {
      int pos = k & (half - 1);
      int grp = k >> (s - 1);
      int i0 = (grp << s) + pos;
      int i1 = i0 + half;
      int j = pos << (11 - s);
      float wr = twr[j], wi = twi[j];
      float ur = re[i0], ui = im[i0];
      float vr = re[i1], vi = im[i1];
      re[i0] = ur + vr; im[i0] = ui + vi;
      float dr = ur - vr, di = ui - vi;
      re[i1] = dr * wr - di * wi;
      im[i1] = dr * wi + di * wr;
    }
    __syncthreads();
  }

  // elementwise spectral filter (order-independent)
  const float SC = 0.022097086912079608f; // 1/sqrt(2048)
  const float fa = fr[c2 * 129];
  const float fb = fi[c2 * 129];
  const float fra = frb[c2];
  const float fia = fib[c2];
  for (int t = tid; t < 2048; t += 256) {
    float rr = re[t] * SC, ii = im[t] * SC;
    re[t] = fmaxf(rr * fa - ii * fb + fra, 0.f);
    im[t] = fmaxf(ii * fa + rr * fb + fia, 0.f);
  }
  __syncthreads();

  // inverse DIT: bit-reversed in -> natural out
  for (int s = 1; s <= 11; ++s) {
    const int half = 1 << (s - 1);
    for (int k = tid; k < 1024; k += 256) {
      int pos = k & (half - 1);
      int grp = k >> (s - 1);
      int i0 = (grp << s) + pos;
      int i1 = i0 + half;
      int j = pos << (11 - s);
      float wr = twr[j], wi = -twi[j];
      float xr = re[i1], xi = im[i1];
      float tr = xr * wr - xi * wi;
      float ti = xr * wi + xi * wr;
      float ur = re[i0], ui = im[i0];
      re[i0] = ur + tr; im[i0] = ui + ti;
      re[i1] = ur - tr; im[i1] = ui - ti;
    }
    __syncthreads();
  }

  float* grow = g_c + ((size_t)(b * 128 + c2)) * T;
  for (int t = tid; t < 2048; t += 256)
    grow[t] = re[t] * SC;
}

// ---------------------------------------------------------------- kernel 6: fc2 + bn + final residual -> d_out (B,64,T)
__global__ __launch_bounds__(256) void k_out(
    const float* __restrict__ g_c, const float* __restrict__ xres,
    const float* __restrict__ fc2_w, const float* __restrict__ bn2_g, const float* __restrict__ bn2_b,
    float* __restrict__ out)
{
  const int b = blockIdx.y;
  const int t0 = blockIdx.x * 16;
  const int tid = threadIdx.x;
  const float INVS = bnscale();

  __shared__ float gl[16][129];
  __shared__ float w2[128][65];   // fc2_w transposed: w2[cc][c]
  __shared__ float res[64][17];

  for (int i = tid; i < 2048; i += 256) {
    int tt = i & 15, cc = i >> 4;
    gl[tt][cc] = g_c[((size_t)(b * 128 + cc)) * T + t0 + tt];
  }
  for (int i = tid; i < 8192; i += 256) {
    int c = i >> 7, cc = i & 127;
    w2[cc][c] = fc2_w[i];
  }
  __syncthreads();

  {
    const int c = tid & 63, grp = tid >> 6;
    float a0 = 0.f, a1 = 0.f, a2 = 0.f, a3 = 0.f;
    for (int cc = 0; cc < 128; ++cc) {
      float wv = w2[cc][c];
      a0 += wv * gl[grp * 4 + 0][cc];
      a1 += wv * gl[grp * 4 + 1][cc];
      a2 += wv * gl[grp * 4 + 2][cc];
      a3 += wv * gl[grp * 4 + 3][cc];
    }
    float g2 = bn2_g[c] * INVS, b2 = bn2_b[c];
    float av[4] = {a0, a1, a2, a3};
#pragma unroll
    for (int j = 0; j < 4; ++j) {
      int tt = grp * 4 + j;
      res[c][tt] = xres[((size_t)(b * T + t0 + tt)) * 64 + c] + av[j] * g2 + b2;
    }
  }
  __syncthreads();

  for (int i = tid; i < 1024; i += 256) {
    int tt = i & 15, c = i >> 4;
    out[(size_t)(b * 64 + c) * T + t0 + tt] = res[c][tt];
  }
}

// ----------------------------------------------------------------
extern "C" void kernel_launch(void* const* d_in, const int* in_sizes, int n_in,
                              void* d_out, int out_size, void* d_ws, size_t ws_size,
                              hipStream_t stream) {
  (void)in_sizes; (void)n_in; (void)out_size; (void)ws_size;
  const float* x     = (const float*)d_in[0];
  const float* n1_g  = (const float*)d_in[1];
  const float* n1_b  = (const float*)d_in[2];
  const float* wq    = (const float*)d_in[3];
  const float* bnq_g = (const float*)d_in[4];
  const float* bnq_b = (const float*)d_in[5];
  const float* wk    = (const float*)d_in[6];
  const float* bnk_g = (const float*)d_in[7];
  const float* bnk_b = (const float*)d_in[8];
  const float* wv    = (const float*)d_in[9];
  const float* lepe_w= (const float*)d_in[10];
  const float* lepe_b= (const float*)d_in[11];
  const float* out_w = (const float*)d_in[12];
  const float* out_b = (const float*)d_in[13];
  const float* n2_g  = (const float*)d_in[14];
  const float* n2_b  = (const float*)d_in[15];
  const float* fc1_w = (const float*)d_in[16];
  const float* bn1_g = (const float*)d_in[17];
  const float* bn1_b = (const float*)d_in[18];
  const float* fr    = (const float*)d_in[19];
  const float* fi    = (const float*)d_in[20];
  const float* frb   = (const float*)d_in[21];
  const float* fib   = (const float*)d_in[22];
  const float* fc2_w = (const float*)d_in[23];
  const float* bn2_g = (const float*)d_in[24];
  const float* bn2_b = (const float*)d_in[25];

  float* out = (float*)d_out;
  float* ws  = (float*)d_ws;
  const size_t M1 = (size_t)1 << 20;

  float* q_t  = ws;            // 2M floats
  float* k_t  = ws + 2 * M1;   // 2M
  float* v_t  = ws + 4 * M1;   // 2M
  float* q_rc = ws + 6 * M1;   // 1M  (c-major [b][c][r])
  float* k_rc = ws + 7 * M1;   // 1M
  float* o_t  = ws + 8 * M1;   // 2M
  float* xrs  = ws + 10 * M1;  // 2M
  int*   sel  = (int*)(ws + 12 * M1); // 0.64M ints
  float* h_c  = ws;            // 4M c-major [b][cc][t], reuses q_t+k_t (dead after k_attn)
  float* g_c  = ws + 4 * M1;   // 4M c-major, reuses v_t+q_rc+k_rc

  k_qkv<<<dim3(32, 16), 256, 0, stream>>>(x, n1_g, n1_b, wq, bnq_g, bnq_b,
                                          wk, bnk_g, bnk_b, wv, q_t, k_t, v_t, q_rc, k_rc);
  k_scores<<<dim3(256, 16), 256, 0, stream>>>(q_rc, k_rc, sel);
  k_attn<<<dim3(1024, 16), 256, 0, stream>>>(q_t, k_t, v_t, sel, lepe_w, lepe_b, o_t);
  k_mix<<<dim3(128, 16), 256, 0, stream>>>(x, o_t, out_w, out_b, n2_g, n2_b,
                                           fc1_w, bn1_g, bn1_b, xrs, h_c);
  k_fft<<<dim3(128, 16), 256, 0, stream>>>(h_c, fr, fi, frb, fib, g_c);
  k_out<<<dim3(128, 16), 256, 0, stream>>>(g_c, xrs, fc2_w, bn2_g, bn2_b, out);
}